// Round 4
// baseline (40.713 us; speedup 1.0000x reference)
//
#include <hip/hip_runtime.h>

// ---------------------------------------------------------------------------
// Single-kernel SO(3) convolution. Compile-time real-SH Clebsch-Gordan table
// (LMAX=2) so the path contraction fully unrolls into register FMAs.
// Each block = one receiving atom; it finds its own edges by scanning idx_i
// (deterministic two-pass compaction, no atomics, no workspace, no memset).
// ---------------------------------------------------------------------------

#define SH_N 9
#define NB 128
#define NR 20
#define NSUB 4
#define NT (NSUB * NB)      // 512 threads
#define CAPL 128            // max edges per atom held in LDS (Poisson(10); max ~28)

namespace cgc {

struct CD { double re, im; };
constexpr CD cmul(CD x, CD y) { return {x.re * y.re - x.im * y.im, x.re * y.im + x.im * y.re}; }
constexpr CD cadd(CD x, CD y) { return {x.re + y.re, x.im + y.im}; }
constexpr CD cconj(CD x) { return {x.re, -x.im}; }

constexpr double FACT[10] = {1., 1., 2., 6., 24., 120., 720., 5040., 40320., 362880.};

constexpr double csqrt(double a) {
    if (a <= 0.0) return 0.0;
    double x = a < 1.0 ? 1.0 : a;
    for (int i = 0; i < 40; ++i) x = 0.5 * (x + a / x);
    return x;
}

constexpr double cg_complex(int l1, int m1, int l2, int m2, int l3, int m3) {
    if (m3 != m1 + m2) return 0.0;
    int dl = l1 > l2 ? l1 - l2 : l2 - l1;
    if (l3 < dl || l3 > l1 + l2) return 0.0;
    double pre = csqrt((2.0 * l3 + 1.0) * FACT[l3 + l1 - l2] * FACT[l3 - l1 + l2]
                       * FACT[l1 + l2 - l3] / FACT[l1 + l2 + l3 + 1]);
    pre = pre * csqrt(FACT[l3 + m3] * FACT[l3 - m3] * FACT[l1 - m1] * FACT[l1 + m1]
                      * FACT[l2 - m2] * FACT[l2 + m2]);
    int kmin = 0;
    if (l2 - l3 - m1 > kmin) kmin = l2 - l3 - m1;
    if (l1 - l3 + m2 > kmin) kmin = l1 - l3 + m2;
    int kmax = l1 + l2 - l3;
    if (l1 - m1 < kmax) kmax = l1 - m1;
    if (l2 + m2 < kmax) kmax = l2 + m2;
    double s = 0.0;
    for (int k = kmin; k <= kmax; ++k) {
        double term = 1.0 / (FACT[k] * FACT[l1 + l2 - l3 - k] * FACT[l1 - m1 - k]
                             * FACT[l2 + m2 - k] * FACT[l3 - l2 + m1 + k] * FACT[l3 - l1 - m2 + k]);
        s += (k & 1) ? -term : term;
    }
    return pre * s;
}

struct U5 { CD m[5][5]; };
constexpr U5 u_c2r(int l) {
    U5 u{};
    const double isq = csqrt(0.5);
    u.m[l][l] = {1.0, 0.0};
    for (int mm = 1; mm <= l; ++mm) {
        double sgn = (mm & 1) ? -1.0 : 1.0;
        u.m[l + mm][l + mm] = {sgn * isq, 0.0};
        u.m[l + mm][l - mm] = {isq, 0.0};
        u.m[l - mm][l - mm] = {0.0, isq};
        u.m[l - mm][l + mm] = {0.0, -sgn * isq};
    }
    return u;
}

struct CGTab { float v[SH_N][SH_N][SH_N]; };   // [i1_dir][i2_x][i_out]

constexpr CGTab build_cg() {
    CGTab t{};
    for (int l1 = 0; l1 <= 2; ++l1)
    for (int l2 = 0; l2 <= 2; ++l2)
    for (int l3 = 0; l3 <= 2; ++l3) {
        int dl = l1 > l2 ? l1 - l2 : l2 - l1;
        if (((l1 + l2 + l3) & 1) || l3 < dl || l3 > l1 + l2) continue;
        U5 U1 = u_c2r(l1), U2 = u_c2r(l2), U3 = u_c2r(l3);
        const int n1 = 2 * l1 + 1, n2 = 2 * l2 + 1, n3 = 2 * l3 + 1;
        double blk[5][5][5] = {};
        for (int a = 0; a < n1; ++a)
        for (int b = 0; b < n2; ++b) {
            int m1 = a - l1, m2 = b - l2, m3 = m1 + m2;
            if (m3 < -l3 || m3 > l3) continue;
            blk[a][b][m3 + l3] = cg_complex(l1, m1, l2, m2, l3, m3);
        }
        for (int i = 0; i < n1; ++i)
        for (int j = 0; j < n2; ++j)
        for (int k = 0; k < n3; ++k) {
            CD s{0.0, 0.0};
            for (int a = 0; a < n1; ++a) {
                if (U1.m[i][a].re == 0.0 && U1.m[i][a].im == 0.0) continue;
                for (int b = 0; b < n2; ++b) {
                    if (U2.m[j][b].re == 0.0 && U2.m[j][b].im == 0.0) continue;
                    int m3 = (a - l1) + (b - l2);
                    if (m3 < -l3 || m3 > l3) continue;
                    double B = blk[a][b][m3 + l3];
                    if (B == 0.0) continue;
                    CD u3 = cconj(U3.m[k][m3 + l3]);
                    if (u3.re == 0.0 && u3.im == 0.0) continue;
                    CD term = cmul(cmul(U1.m[i][a], U2.m[j][b]), u3);
                    s = cadd(s, CD{term.re * B, term.im * B});
                }
            }
            double v = s.re;
            if (v < 1e-12 && v > -1e-12) v = 0.0;
            t.v[l1 * l1 + i][l2 * l2 + j][l3 * l3 + k] = (float)v;
        }
    }
    return t;
}

} // namespace cgc

static constexpr cgc::CGTab CGT = cgc::build_cg();

// degree of SH index a: 0 -> l0, 1..3 -> l1, 4..8 -> l2 (compile-time in unrolled loops)
__device__ __forceinline__ float sel_w(int a, float w0, float w1, float w2) {
    return (a == 0) ? w0 : ((a < 4) ? w1 : w2);
}

// ---------------------------------------------------------------------------

__global__ void __launch_bounds__(NT)
so3_fused_kernel(const float* __restrict__ x,
                 const float* __restrict__ radial,
                 const float* __restrict__ dir,
                 const float* __restrict__ cutoff,
                 const float* __restrict__ Wf,
                 const float* __restrict__ bf,
                 const int* __restrict__ idx_i,
                 const int* __restrict__ idx_j,
                 float* __restrict__ y,
                 int E) {
    const int a    = blockIdx.x;
    const int tid  = threadIdx.x;
    const int sub  = tid >> 7;          // 0..3
    const int c    = tid & (NB - 1);    // basis channel 0..127
    const int lane = tid & 63;
    const int wid  = tid >> 6;          // 0..7

    __shared__ int s_list[CAPL];
    __shared__ int s_wsum[8];
    __shared__ int s_m;

    // ---- phase A: find this atom's edges (deterministic, ascending edge id) ----
    const int chunk = (E + NT - 1) / NT;
    const int ebeg  = tid * chunk;
    const int eend  = (ebeg + chunk < E) ? (ebeg + chunk) : E;

    int cnt = 0;
    for (int k = ebeg; k < eend; ++k) cnt += (idx_i[k] == a);

    // wave-inclusive prefix sum of cnt
    int v = cnt;
#pragma unroll
    for (int d = 1; d < 64; d <<= 1) {
        int u = __shfl_up(v, d);
        if (lane >= d) v += u;
    }
    if (lane == 63) s_wsum[wid] = v;
    __syncthreads();
    if (tid == 0) {
        int t = 0;
#pragma unroll
        for (int w = 0; w < 8; ++w) { int q = s_wsum[w]; s_wsum[w] = t; t += q; }
        s_m = t;
    }
    __syncthreads();
    int off = s_wsum[wid] + v - cnt;    // exclusive prefix across block
    if (cnt > 0) {
        for (int k = ebeg; k < eend; ++k)            // re-scan (L1-hot)
            if (idx_i[k] == a && off < CAPL) s_list[off++] = k;
    }
    __syncthreads();
    int m = s_m;
    if (m > CAPL) m = CAPL;

    // ---- phase B: per-sub edge processing, all register-resident ----
    float acc[SH_N];
#pragma unroll
    for (int o = 0; o < SH_N; ++o) acc[o] = 0.f;

    const float b0 = bf[c], b1 = bf[NB + c], b2 = bf[2 * NB + c];

    for (int ie = sub; ie < m; ie += NSUB) {
        const int e = s_list[ie];
        const int aj = idx_j[e];
        const float cut = cutoff[e];

        // direction SH (wave-uniform broadcast loads)
        float d[SH_N];
#pragma unroll
        for (int k = 0; k < SH_N; ++k) d[k] = dir[(size_t)e * SH_N + k];

        // neighbor feature row -> registers
        float xr[SH_N];
        const float* xp = x + (size_t)aj * (SH_N * NB) + c;
#pragma unroll
        for (int k = 0; k < SH_N; ++k) xr[k] = xp[k * NB];

        // radial filter (Wf is 30 KB, L1-resident)
        float w0 = b0, w1 = b1, w2 = b2;
        const float* rad = radial + (size_t)e * NR;
        const float* wfc = Wf + c;
#pragma unroll
        for (int r = 0; r < NR; ++r) {
            const float rv = rad[r];
            w0 = fmaf(rv, wfc[r * 3 * NB], w0);
            w1 = fmaf(rv, wfc[r * 3 * NB + NB], w1);
            w2 = fmaf(rv, wfc[r * 3 * NB + 2 * NB], w2);
        }
        w0 *= cut; w1 *= cut; w2 *= cut;

        // CG contraction, fully unrolled; zero entries fold away at compile time
#pragma unroll
        for (int ai = 0; ai < SH_N; ++ai) {
            const float daw = d[ai] * sel_w(ai, w0, w1, w2);
#pragma unroll
            for (int bi = 0; bi < SH_N; ++bi) {
                const float g = daw * xr[bi];
#pragma unroll
                for (int o = 0; o < SH_N; ++o) {
                    if (CGT.v[ai][bi][o] != 0.0f)
                        acc[o] = fmaf(CGT.v[ai][bi][o], g, acc[o]);
                }
            }
        }
    }

    // ---- phase C: cross-sub reduction + single coalesced write ----
    __shared__ float s_red[NSUB][SH_N * NB];
#pragma unroll
    for (int o = 0; o < SH_N; ++o) s_red[sub][o * NB + c] = acc[o];
    __syncthreads();
    for (int oc = tid; oc < SH_N * NB; oc += NT) {
        float out = s_red[0][oc] + s_red[1][oc] + s_red[2][oc] + s_red[3][oc];
        y[(size_t)a * (SH_N * NB) + oc] = out;
    }
}

// ---------------------------------------------------------------------------

extern "C" void kernel_launch(void* const* d_in, const int* in_sizes, int n_in,
                              void* d_out, int out_size, void* d_ws, size_t ws_size,
                              hipStream_t stream) {
    const float* x      = (const float*)d_in[0];
    const float* radial = (const float*)d_in[1];
    const float* dir    = (const float*)d_in[2];
    const float* cutoff = (const float*)d_in[3];
    const float* Wf     = (const float*)d_in[4];
    const float* bf     = (const float*)d_in[5];
    const int*   idx_i  = (const int*)d_in[6];
    const int*   idx_j  = (const int*)d_in[7];
    float* y = (float*)d_out;
    const int E = in_sizes[6];
    const int n_atoms = out_size / (SH_N * NB);

    so3_fused_kernel<<<n_atoms, NT, 0, stream>>>(x, radial, dir, cutoff, Wf, bf,
                                                 idx_i, idx_j, y, E);
}

// Round 5
// 28.876 us; speedup vs baseline: 1.4099x; 1.4099x over previous
//
#include <hip/hip_runtime.h>

// ---------------------------------------------------------------------------
// Single-kernel SO(3) convolution (LMAX=2). Compile-time real-SH CG table so
// the contraction unrolls into register FMAs. One block per receiving atom;
// block finds its edges by a coalesced bitmask scan of idx_i (deterministic,
// no atomics, no workspace). Wf column lives in VGPRs (read once per block).
// Explicit 1-deep A/B software pipeline hides the x-row gather latency.
// ---------------------------------------------------------------------------

#define SH_N 9
#define NB 128
#define NR 20
#define NSUB 2
#define NT (NSUB * NB)      // 256 threads
#define CAPL 128            // max edges per atom (Poisson(10); max ~28)

namespace cgc {

struct CD { double re, im; };
constexpr CD cmul(CD x, CD y) { return {x.re * y.re - x.im * y.im, x.re * y.im + x.im * y.re}; }
constexpr CD cadd(CD x, CD y) { return {x.re + y.re, x.im + y.im}; }
constexpr CD cconj(CD x) { return {x.re, -x.im}; }

constexpr double FACT[10] = {1., 1., 2., 6., 24., 120., 720., 5040., 40320., 362880.};

constexpr double csqrt(double a) {
    if (a <= 0.0) return 0.0;
    double x = a < 1.0 ? 1.0 : a;
    for (int i = 0; i < 40; ++i) x = 0.5 * (x + a / x);
    return x;
}

constexpr double cg_complex(int l1, int m1, int l2, int m2, int l3, int m3) {
    if (m3 != m1 + m2) return 0.0;
    int dl = l1 > l2 ? l1 - l2 : l2 - l1;
    if (l3 < dl || l3 > l1 + l2) return 0.0;
    double pre = csqrt((2.0 * l3 + 1.0) * FACT[l3 + l1 - l2] * FACT[l3 - l1 + l2]
                       * FACT[l1 + l2 - l3] / FACT[l1 + l2 + l3 + 1]);
    pre = pre * csqrt(FACT[l3 + m3] * FACT[l3 - m3] * FACT[l1 - m1] * FACT[l1 + m1]
                      * FACT[l2 - m2] * FACT[l2 + m2]);
    int kmin = 0;
    if (l2 - l3 - m1 > kmin) kmin = l2 - l3 - m1;
    if (l1 - l3 + m2 > kmin) kmin = l1 - l3 + m2;
    int kmax = l1 + l2 - l3;
    if (l1 - m1 < kmax) kmax = l1 - m1;
    if (l2 + m2 < kmax) kmax = l2 + m2;
    double s = 0.0;
    for (int k = kmin; k <= kmax; ++k) {
        double term = 1.0 / (FACT[k] * FACT[l1 + l2 - l3 - k] * FACT[l1 - m1 - k]
                             * FACT[l2 + m2 - k] * FACT[l3 - l2 + m1 + k] * FACT[l3 - l1 - m2 + k]);
        s += (k & 1) ? -term : term;
    }
    return pre * s;
}

struct U5 { CD m[5][5]; };
constexpr U5 u_c2r(int l) {
    U5 u{};
    const double isq = csqrt(0.5);
    u.m[l][l] = {1.0, 0.0};
    for (int mm = 1; mm <= l; ++mm) {
        double sgn = (mm & 1) ? -1.0 : 1.0;
        u.m[l + mm][l + mm] = {sgn * isq, 0.0};
        u.m[l + mm][l - mm] = {isq, 0.0};
        u.m[l - mm][l - mm] = {0.0, isq};
        u.m[l - mm][l + mm] = {0.0, -sgn * isq};
    }
    return u;
}

struct CGTab { float v[SH_N][SH_N][SH_N]; };   // [i1_dir][i2_x][i_out]

constexpr CGTab build_cg() {
    CGTab t{};
    for (int l1 = 0; l1 <= 2; ++l1)
    for (int l2 = 0; l2 <= 2; ++l2)
    for (int l3 = 0; l3 <= 2; ++l3) {
        int dl = l1 > l2 ? l1 - l2 : l2 - l1;
        if (((l1 + l2 + l3) & 1) || l3 < dl || l3 > l1 + l2) continue;
        U5 U1 = u_c2r(l1), U2 = u_c2r(l2), U3 = u_c2r(l3);
        const int n1 = 2 * l1 + 1, n2 = 2 * l2 + 1, n3 = 2 * l3 + 1;
        double blk[5][5][5] = {};
        for (int a = 0; a < n1; ++a)
        for (int b = 0; b < n2; ++b) {
            int m1 = a - l1, m2 = b - l2, m3 = m1 + m2;
            if (m3 < -l3 || m3 > l3) continue;
            blk[a][b][m3 + l3] = cg_complex(l1, m1, l2, m2, l3, m3);
        }
        for (int i = 0; i < n1; ++i)
        for (int j = 0; j < n2; ++j)
        for (int k = 0; k < n3; ++k) {
            CD s{0.0, 0.0};
            for (int a = 0; a < n1; ++a) {
                if (U1.m[i][a].re == 0.0 && U1.m[i][a].im == 0.0) continue;
                for (int b = 0; b < n2; ++b) {
                    if (U2.m[j][b].re == 0.0 && U2.m[j][b].im == 0.0) continue;
                    int m3 = (a - l1) + (b - l2);
                    if (m3 < -l3 || m3 > l3) continue;
                    double B = blk[a][b][m3 + l3];
                    if (B == 0.0) continue;
                    CD u3 = cconj(U3.m[k][m3 + l3]);
                    if (u3.re == 0.0 && u3.im == 0.0) continue;
                    CD term = cmul(cmul(U1.m[i][a], U2.m[j][b]), u3);
                    s = cadd(s, CD{term.re * B, term.im * B});
                }
            }
            double v = s.re;
            if (v < 1e-12 && v > -1e-12) v = 0.0;
            t.v[l1 * l1 + i][l2 * l2 + j][l3 * l3 + k] = (float)v;
        }
    }
    return t;
}

} // namespace cgc

static constexpr cgc::CGTab CGT = cgc::build_cg();

__device__ __forceinline__ float sel_w(int a, float w0, float w1, float w2) {
    return (a == 0) ? w0 : ((a < 4) ? w1 : w2);
}
__device__ __forceinline__ float f4c(const float4& v, int j) {
    return j == 0 ? v.x : (j == 1 ? v.y : (j == 2 ? v.z : v.w));
}

// per-edge register set (all indices static -> stays in VGPRs)
struct EdgeSet {
    float xr[SH_N];
    float d[SH_N];
    float4 r[5];
    float cut;
    float w0, w1, w2;
};

__device__ __forceinline__ void load_set(EdgeSet& s, int e,
        const float* __restrict__ x, const float* __restrict__ dir,
        const float* __restrict__ radial, const float* __restrict__ cutoff,
        const int* __restrict__ idx_j, int c) {
    const int aj = idx_j[e];
    const float* xp = x + (size_t)aj * (SH_N * NB) + c;
#pragma unroll
    for (int k = 0; k < SH_N; ++k) s.xr[k] = xp[k * NB];
    const float* dp = dir + (size_t)e * SH_N;
#pragma unroll
    for (int k = 0; k < SH_N; ++k) s.d[k] = dp[k];
    const float4* rp = (const float4*)(radial + (size_t)e * NR);
#pragma unroll
    for (int k = 0; k < 5; ++k) s.r[k] = rp[k];
    s.cut = cutoff[e];
}

__device__ __forceinline__ void wcomp(EdgeSet& s, const float (&wreg)[NR * 3],
                                      float b0, float b1, float b2) {
    float a0 = b0, a1 = b1, a2 = b2;
#pragma unroll
    for (int r = 0; r < NR; ++r) {
        const float rv = f4c(s.r[r >> 2], r & 3);
        a0 = fmaf(rv, wreg[r * 3 + 0], a0);
        a1 = fmaf(rv, wreg[r * 3 + 1], a1);
        a2 = fmaf(rv, wreg[r * 3 + 2], a2);
    }
    s.w0 = a0 * s.cut; s.w1 = a1 * s.cut; s.w2 = a2 * s.cut;
}

__device__ __forceinline__ void cg_acc(const EdgeSet& s, float (&acc)[SH_N]) {
#pragma unroll
    for (int ai = 0; ai < SH_N; ++ai) {
        const float daw = s.d[ai] * sel_w(ai, s.w0, s.w1, s.w2);
#pragma unroll
        for (int bi = 0; bi < SH_N; ++bi) {
            const float g = daw * s.xr[bi];
#pragma unroll
            for (int o = 0; o < SH_N; ++o)
                if (CGT.v[ai][bi][o] != 0.0f)
                    acc[o] = fmaf(CGT.v[ai][bi][o], g, acc[o]);
        }
    }
}

// ---------------------------------------------------------------------------

__global__ void __launch_bounds__(NT)
so3_fused_kernel(const float* __restrict__ x,
                 const float* __restrict__ radial,
                 const float* __restrict__ dir,
                 const float* __restrict__ cutoff,
                 const float* __restrict__ Wf,
                 const float* __restrict__ bf,
                 const int* __restrict__ idx_i,
                 const int* __restrict__ idx_j,
                 float* __restrict__ y,
                 int E) {
    const int a    = blockIdx.x;
    const int tid  = threadIdx.x;
    const int sub  = tid >> 7;          // 0..1
    const int c    = tid & (NB - 1);    // basis channel
    const int lane = tid & 63;
    const int wid  = tid >> 6;          // 0..3

    __shared__ int s_list[CAPL];
    __shared__ int s_wsum[NT / 64];
    __shared__ int s_m;

    // Wf column + bias -> registers, reused for every edge of this block
    float wreg[NR * 3];
#pragma unroll
    for (int r = 0; r < NR; ++r)
#pragma unroll
        for (int l = 0; l < 3; ++l)
            wreg[r * 3 + l] = Wf[(r * 3 + l) * NB + c];
    const float b0 = bf[c], b1 = bf[NB + c], b2 = bf[2 * NB + c];

    // ---- phase A: find this atom's edges via coalesced int4 + bitmask ----
    unsigned long long mask = 0ull;
    int cnt = 0;
    const int E4 = E >> 2;
    const bool fast_scan = (4 * ((E4 + NT - 1) / NT) <= 60);
    if (fast_scan) {
        const int4* p4 = (const int4*)idx_i;
        int b = 0;
        for (int k4 = tid; k4 < E4; k4 += NT, ++b) {
            const int4 q = p4[k4];
            unsigned long long h = (unsigned long long)(q.x == a)
                                 | ((unsigned long long)(q.y == a) << 1)
                                 | ((unsigned long long)(q.z == a) << 2)
                                 | ((unsigned long long)(q.w == a) << 3);
            mask |= h << (4 * b);
        }
        // tail edges (E%4 < 4): thread t checks edge 4*E4+t, bit 60+t
        const int kt = 4 * E4 + tid;
        if (tid < (E & 3) && kt < E && idx_i[kt] == a)
            mask |= 1ull << (60 + tid);
        cnt = __popcll(mask);
    } else {
        for (int k = tid; k < E; k += NT) cnt += (idx_i[k] == a);
    }

    // block exclusive prefix over cnt
    int v = cnt;
#pragma unroll
    for (int d = 1; d < 64; d <<= 1) {
        int u = __shfl_up(v, d);
        if (lane >= d) v += u;
    }
    if (lane == 63) s_wsum[wid] = v;
    __syncthreads();
    if (tid == 0) {
        int t = 0;
#pragma unroll
        for (int w = 0; w < NT / 64; ++w) { int q = s_wsum[w]; s_wsum[w] = t; t += q; }
        s_m = t;
    }
    __syncthreads();
    int off = s_wsum[wid] + v - cnt;

    if (fast_scan) {
        unsigned long long mm = mask;
        while (mm) {
            const int p = __ffsll(mm) - 1;
            mm &= mm - 1;
            int k;
            if (p >= 60) k = 4 * E4 + (p - 60);
            else         k = 4 * (tid + (p >> 2) * NT) + (p & 3);
            if (off < CAPL) s_list[off] = k;
            ++off;
        }
    } else if (cnt > 0) {
        for (int k = tid; k < E; k += NT)
            if (idx_i[k] == a) { if (off < CAPL) s_list[off] = k; ++off; }
    }
    __syncthreads();
    const int m = (s_m < CAPL) ? s_m : CAPL;

    // ---- phase B: software-pipelined edge loop, all register-resident ----
    float acc[SH_N];
#pragma unroll
    for (int o = 0; o < SH_N; ++o) acc[o] = 0.f;

    int ie = sub;
    if (ie < m) {
        EdgeSet A, B;
        load_set(A, s_list[ie], x, dir, radial, cutoff, idx_j, c);
        wcomp(A, wreg, b0, b1, b2);
        for (;;) {
            int ien = ie + NSUB;
            if (ien < m) {
                load_set(B, s_list[ien], x, dir, radial, cutoff, idx_j, c);
                cg_acc(A, acc);            // hides B's gather latency
                wcomp(B, wreg, b0, b1, b2);
                ie = ien; ien += NSUB;
                if (ien < m) {
                    load_set(A, s_list[ien], x, dir, radial, cutoff, idx_j, c);
                    cg_acc(B, acc);
                    wcomp(A, wreg, b0, b1, b2);
                    ie = ien;
                } else { cg_acc(B, acc); break; }
            } else { cg_acc(A, acc); break; }
        }
    }

    // ---- phase C: 2-way cross-sub reduce + coalesced write ----
    __shared__ float s_red[NSUB][SH_N * NB];
#pragma unroll
    for (int o = 0; o < SH_N; ++o) s_red[sub][o * NB + c] = acc[o];
    __syncthreads();
    float* yo = y + (size_t)a * (SH_N * NB);
    for (int oc = tid; oc < SH_N * NB; oc += NT)
        yo[oc] = s_red[0][oc] + s_red[1][oc];
}

// ---------------------------------------------------------------------------

extern "C" void kernel_launch(void* const* d_in, const int* in_sizes, int n_in,
                              void* d_out, int out_size, void* d_ws, size_t ws_size,
                              hipStream_t stream) {
    const float* x      = (const float*)d_in[0];
    const float* radial = (const float*)d_in[1];
    const float* dir    = (const float*)d_in[2];
    const float* cutoff = (const float*)d_in[3];
    const float* Wf     = (const float*)d_in[4];
    const float* bf     = (const float*)d_in[5];
    const int*   idx_i  = (const int*)d_in[6];
    const int*   idx_j  = (const int*)d_in[7];
    float* y = (float*)d_out;
    const int E = in_sizes[6];
    const int n_atoms = out_size / (SH_N * NB);

    so3_fused_kernel<<<n_atoms, NT, 0, stream>>>(x, radial, dir, cutoff, Wf, bf,
                                                 idx_i, idx_j, y, E);
}

// Round 6
// 26.280 us; speedup vs baseline: 1.5492x; 1.0988x over previous
//
#include <hip/hip_runtime.h>

// ---------------------------------------------------------------------------
// Single-kernel SO(3) convolution (LMAX=2). Compile-time real-SH CG table so
// the contraction unrolls into register FMAs. One block (256 thr) per atom:
//   A) coalesced bitmask scan of idx_i -> edge list in LDS (deterministic)
//   B) 2 sub-groups x 128 channels; per-edge uniform params (radial/dir/cut)
//      forced to SGPRs via readfirstlane'd edge id; only the x-row gather is
//      vector. 1-deep software pipeline hides gather latency.
//   C) cross-sub LDS reduce + single coalesced write.
// __launch_bounds__(256,4): <=128 VGPR -> 4 blocks/CU -> all atoms co-resident.
// ---------------------------------------------------------------------------

#define SH_N 9
#define NB 128
#define NR 20
#define NSUB 2
#define NT (NSUB * NB)      // 256 threads
#define CAPL 128            // max edges per atom (Poisson(10); max ~28)

namespace cgc {

struct CD { double re, im; };
constexpr CD cmul(CD x, CD y) { return {x.re * y.re - x.im * y.im, x.re * y.im + x.im * y.re}; }
constexpr CD cadd(CD x, CD y) { return {x.re + y.re, x.im + y.im}; }
constexpr CD cconj(CD x) { return {x.re, -x.im}; }

constexpr double FACT[10] = {1., 1., 2., 6., 24., 120., 720., 5040., 40320., 362880.};

constexpr double csqrt(double a) {
    if (a <= 0.0) return 0.0;
    double x = a < 1.0 ? 1.0 : a;
    for (int i = 0; i < 40; ++i) x = 0.5 * (x + a / x);
    return x;
}

constexpr double cg_complex(int l1, int m1, int l2, int m2, int l3, int m3) {
    if (m3 != m1 + m2) return 0.0;
    int dl = l1 > l2 ? l1 - l2 : l2 - l1;
    if (l3 < dl || l3 > l1 + l2) return 0.0;
    double pre = csqrt((2.0 * l3 + 1.0) * FACT[l3 + l1 - l2] * FACT[l3 - l1 + l2]
                       * FACT[l1 + l2 - l3] / FACT[l1 + l2 + l3 + 1]);
    pre = pre * csqrt(FACT[l3 + m3] * FACT[l3 - m3] * FACT[l1 - m1] * FACT[l1 + m1]
                      * FACT[l2 - m2] * FACT[l2 + m2]);
    int kmin = 0;
    if (l2 - l3 - m1 > kmin) kmin = l2 - l3 - m1;
    if (l1 - l3 + m2 > kmin) kmin = l1 - l3 + m2;
    int kmax = l1 + l2 - l3;
    if (l1 - m1 < kmax) kmax = l1 - m1;
    if (l2 + m2 < kmax) kmax = l2 + m2;
    double s = 0.0;
    for (int k = kmin; k <= kmax; ++k) {
        double term = 1.0 / (FACT[k] * FACT[l1 + l2 - l3 - k] * FACT[l1 - m1 - k]
                             * FACT[l2 + m2 - k] * FACT[l3 - l2 + m1 + k] * FACT[l3 - l1 - m2 + k]);
        s += (k & 1) ? -term : term;
    }
    return pre * s;
}

struct U5 { CD m[5][5]; };
constexpr U5 u_c2r(int l) {
    U5 u{};
    const double isq = csqrt(0.5);
    u.m[l][l] = {1.0, 0.0};
    for (int mm = 1; mm <= l; ++mm) {
        double sgn = (mm & 1) ? -1.0 : 1.0;
        u.m[l + mm][l + mm] = {sgn * isq, 0.0};
        u.m[l + mm][l - mm] = {isq, 0.0};
        u.m[l - mm][l - mm] = {0.0, isq};
        u.m[l - mm][l + mm] = {0.0, -sgn * isq};
    }
    return u;
}

struct CGTab { float v[SH_N][SH_N][SH_N]; };   // [i1_dir][i2_x][i_out]

constexpr CGTab build_cg() {
    CGTab t{};
    for (int l1 = 0; l1 <= 2; ++l1)
    for (int l2 = 0; l2 <= 2; ++l2)
    for (int l3 = 0; l3 <= 2; ++l3) {
        int dl = l1 > l2 ? l1 - l2 : l2 - l1;
        if (((l1 + l2 + l3) & 1) || l3 < dl || l3 > l1 + l2) continue;
        U5 U1 = u_c2r(l1), U2 = u_c2r(l2), U3 = u_c2r(l3);
        const int n1 = 2 * l1 + 1, n2 = 2 * l2 + 1, n3 = 2 * l3 + 1;
        double blk[5][5][5] = {};
        for (int a = 0; a < n1; ++a)
        for (int b = 0; b < n2; ++b) {
            int m1 = a - l1, m2 = b - l2, m3 = m1 + m2;
            if (m3 < -l3 || m3 > l3) continue;
            blk[a][b][m3 + l3] = cg_complex(l1, m1, l2, m2, l3, m3);
        }
        for (int i = 0; i < n1; ++i)
        for (int j = 0; j < n2; ++j)
        for (int k = 0; k < n3; ++k) {
            CD s{0.0, 0.0};
            for (int a = 0; a < n1; ++a) {
                if (U1.m[i][a].re == 0.0 && U1.m[i][a].im == 0.0) continue;
                for (int b = 0; b < n2; ++b) {
                    if (U2.m[j][b].re == 0.0 && U2.m[j][b].im == 0.0) continue;
                    int m3 = (a - l1) + (b - l2);
                    if (m3 < -l3 || m3 > l3) continue;
                    double B = blk[a][b][m3 + l3];
                    if (B == 0.0) continue;
                    CD u3 = cconj(U3.m[k][m3 + l3]);
                    if (u3.re == 0.0 && u3.im == 0.0) continue;
                    CD term = cmul(cmul(U1.m[i][a], U2.m[j][b]), u3);
                    s = cadd(s, CD{term.re * B, term.im * B});
                }
            }
            double v = s.re;
            if (v < 1e-12 && v > -1e-12) v = 0.0;
            t.v[l1 * l1 + i][l2 * l2 + j][l3 * l3 + k] = (float)v;
        }
    }
    return t;
}

} // namespace cgc

static constexpr cgc::CGTab CGT = cgc::build_cg();

__device__ __forceinline__ float sel_w(int a, float w0, float w1, float w2) {
    return (a == 0) ? w0 : ((a < 4) ? w1 : w2);
}

// Compute one edge's radial filter + CG contraction into acc.
// `e` is wave-uniform (readfirstlane'd) -> all param loads scalarize to
// s_load; only xr (per-lane x-row fragment) occupies VGPRs.
__device__ __forceinline__ void comp_edge(
        int e, const float (&xr)[SH_N],
        const float* __restrict__ radial, const float* __restrict__ dir,
        const float* __restrict__ cutoff,
        const float (&wreg)[NR * 3], float b0, float b1, float b2,
        float (&acc)[SH_N]) {
    const float* rad = radial + (size_t)e * NR;       // uniform base
    float a0 = b0, a1 = b1, a2 = b2;
#pragma unroll
    for (int r = 0; r < NR; ++r) {
        const float rv = rad[r];                      // s_load
        a0 = fmaf(rv, wreg[r * 3 + 0], a0);
        a1 = fmaf(rv, wreg[r * 3 + 1], a1);
        a2 = fmaf(rv, wreg[r * 3 + 2], a2);
    }
    const float cut = cutoff[e];                      // s_load
    const float w0 = a0 * cut, w1 = a1 * cut, w2 = a2 * cut;
    const float* dp = dir + (size_t)e * SH_N;         // uniform base
#pragma unroll
    for (int ai = 0; ai < SH_N; ++ai) {
        const float daw = dp[ai] * sel_w(ai, w0, w1, w2);
#pragma unroll
        for (int bi = 0; bi < SH_N; ++bi) {
            const float g = daw * xr[bi];
#pragma unroll
            for (int o = 0; o < SH_N; ++o)
                if (CGT.v[ai][bi][o] != 0.0f)
                    acc[o] = fmaf(CGT.v[ai][bi][o], g, acc[o]);
        }
    }
}

__device__ __forceinline__ void load_xr(float (&xr)[SH_N], int e,
        const float* __restrict__ x, const int* __restrict__ idx_j, int c) {
    const int aj = idx_j[e];                          // e uniform -> s_load
    const float* xp = x + (size_t)aj * (SH_N * NB) + c;
#pragma unroll
    for (int k = 0; k < SH_N; ++k) xr[k] = xp[k * NB];
}

// ---------------------------------------------------------------------------

__global__ void __launch_bounds__(NT, 4)
so3_fused_kernel(const float* __restrict__ x,
                 const float* __restrict__ radial,
                 const float* __restrict__ dir,
                 const float* __restrict__ cutoff,
                 const float* __restrict__ Wf,
                 const float* __restrict__ bf,
                 const int* __restrict__ idx_i,
                 const int* __restrict__ idx_j,
                 float* __restrict__ y,
                 int E) {
    const int a    = blockIdx.x;
    const int tid  = threadIdx.x;
    const int sub  = tid >> 7;          // 0..1
    const int c    = tid & (NB - 1);    // basis channel
    const int lane = tid & 63;
    const int wid  = tid >> 6;          // 0..3

    __shared__ int s_list[CAPL];
    __shared__ int s_wsum[NT / 64];
    __shared__ int s_m;

    // Wf column + bias -> registers, reused for every edge of this block
    float wreg[NR * 3];
#pragma unroll
    for (int r = 0; r < NR; ++r)
#pragma unroll
        for (int l = 0; l < 3; ++l)
            wreg[r * 3 + l] = Wf[(r * 3 + l) * NB + c];
    const float b0 = bf[c], b1 = bf[NB + c], b2 = bf[2 * NB + c];

    // ---- phase A: find this atom's edges via coalesced int4 + bitmask ----
    unsigned long long mask = 0ull;
    int cnt = 0;
    const int E4 = E >> 2;
    const bool fast_scan = (4 * ((E4 + NT - 1) / NT) <= 60);
    if (fast_scan) {
        const int4* p4 = (const int4*)idx_i;
        int b = 0;
        for (int k4 = tid; k4 < E4; k4 += NT, ++b) {
            const int4 q = p4[k4];
            unsigned long long h = (unsigned long long)(q.x == a)
                                 | ((unsigned long long)(q.y == a) << 1)
                                 | ((unsigned long long)(q.z == a) << 2)
                                 | ((unsigned long long)(q.w == a) << 3);
            mask |= h << (4 * b);
        }
        const int kt = 4 * E4 + tid;
        if (tid < (E & 3) && kt < E && idx_i[kt] == a)
            mask |= 1ull << (60 + tid);
        cnt = __popcll(mask);
    } else {
        for (int k = tid; k < E; k += NT) cnt += (idx_i[k] == a);
    }

    // block exclusive prefix over cnt
    int v = cnt;
#pragma unroll
    for (int d = 1; d < 64; d <<= 1) {
        int u = __shfl_up(v, d);
        if (lane >= d) v += u;
    }
    if (lane == 63) s_wsum[wid] = v;
    __syncthreads();
    if (tid == 0) {
        int t = 0;
#pragma unroll
        for (int w = 0; w < NT / 64; ++w) { int q = s_wsum[w]; s_wsum[w] = t; t += q; }
        s_m = t;
    }
    __syncthreads();
    int off = s_wsum[wid] + v - cnt;

    if (fast_scan) {
        unsigned long long mm = mask;
        while (mm) {
            const int p = __ffsll(mm) - 1;
            mm &= mm - 1;
            int k;
            if (p >= 60) k = 4 * E4 + (p - 60);
            else         k = 4 * (tid + (p >> 2) * NT) + (p & 3);
            if (off < CAPL) s_list[off] = k;
            ++off;
        }
    } else if (cnt > 0) {
        for (int k = tid; k < E; k += NT)
            if (idx_i[k] == a) { if (off < CAPL) s_list[off] = k; ++off; }
    }
    __syncthreads();
    const int m = (s_m < CAPL) ? s_m : CAPL;

    // ---- phase B: pipelined edge loop; uniform params in SGPRs ----
    float acc[SH_N];
#pragma unroll
    for (int o = 0; o < SH_N; ++o) acc[o] = 0.f;

    int ie = sub;
    if (ie < m) {
        float xrA[SH_N], xrB[SH_N];
        int eA = __builtin_amdgcn_readfirstlane(s_list[ie]);
        load_xr(xrA, eA, x, idx_j, c);
        for (;;) {
            int ien = ie + NSUB;
            if (ien < m) {
                const int eB = __builtin_amdgcn_readfirstlane(s_list[ien]);
                load_xr(xrB, eB, x, idx_j, c);      // prefetch next x-row
                comp_edge(eA, xrA, radial, dir, cutoff, wreg, b0, b1, b2, acc);
                ie = ien; ien += NSUB;
                if (ien < m) {
                    eA = __builtin_amdgcn_readfirstlane(s_list[ien]);
                    load_xr(xrA, eA, x, idx_j, c);
                    comp_edge(eB, xrB, radial, dir, cutoff, wreg, b0, b1, b2, acc);
                    ie = ien;
                } else {
                    comp_edge(eB, xrB, radial, dir, cutoff, wreg, b0, b1, b2, acc);
                    break;
                }
            } else {
                comp_edge(eA, xrA, radial, dir, cutoff, wreg, b0, b1, b2, acc);
                break;
            }
        }
    }

    // ---- phase C: 2-way cross-sub reduce + coalesced write ----
    __shared__ float s_red[NSUB][SH_N * NB];
#pragma unroll
    for (int o = 0; o < SH_N; ++o) s_red[sub][o * NB + c] = acc[o];
    __syncthreads();
    float* yo = y + (size_t)a * (SH_N * NB);
    for (int oc = tid; oc < SH_N * NB; oc += NT)
        yo[oc] = s_red[0][oc] + s_red[1][oc];
}

// ---------------------------------------------------------------------------

extern "C" void kernel_launch(void* const* d_in, const int* in_sizes, int n_in,
                              void* d_out, int out_size, void* d_ws, size_t ws_size,
                              hipStream_t stream) {
    const float* x      = (const float*)d_in[0];
    const float* radial = (const float*)d_in[1];
    const float* dir    = (const float*)d_in[2];
    const float* cutoff = (const float*)d_in[3];
    const float* Wf     = (const float*)d_in[4];
    const float* bf     = (const float*)d_in[5];
    const int*   idx_i  = (const int*)d_in[6];
    const int*   idx_j  = (const int*)d_in[7];
    float* y = (float*)d_out;
    const int E = in_sizes[6];
    const int n_atoms = out_size / (SH_N * NB);

    so3_fused_kernel<<<n_atoms, NT, 0, stream>>>(x, radial, dir, cutoff, Wf, bf,
                                                 idx_i, idx_j, y, E);
}